// Round 6
// baseline (274.985 us; speedup 1.0000x reference)
//
#include <hip/hip_runtime.h>
#include <stdint.h>

typedef unsigned short u16;
using bf16x8 = __attribute__((ext_vector_type(8))) short;
using f32x4  = __attribute__((ext_vector_type(4))) float;

#define NORM 0.03125f  // 1/sqrt(1024)

enum { M_PROJ = 0, M_EXP = 1, M_PV = 2, M_OUT = 3 };

__device__ __forceinline__ u16 f2bf(float f) {
  uint32_t u = __float_as_uint(f);
  return (u16)((u + 0x7FFFu + ((u >> 16) & 1u)) >> 16);  // RNE
}

__device__ __forceinline__ void gload_lds16(const void* g, void* lds) {
  __builtin_amdgcn_global_load_lds(
      (const __attribute__((address_space(1))) uint32_t*)g,
      (__attribute__((address_space(3))) uint32_t*)lds, 16, 0, 0);
}

// f32 -> bf16 elementwise, 4 elems/thread
__global__ void k_cvt(const float* __restrict__ in, u16* __restrict__ out, int n4) {
  int i = blockIdx.x * blockDim.x + threadIdx.x;
  if (i >= n4) return;
  float4 v = ((const float4*)in)[i];
  uint32_t lo = f2bf(v.x) | ((uint32_t)f2bf(v.y) << 16);
  uint32_t hi = f2bf(v.z) | ((uint32_t)f2bf(v.w) << 16);
  ((uint2*)out)[i] = make_uint2(lo, hi);
}

// transpose + convert the 4 weight matrices [1024x1024] f32 -> WT[n][k] bf16
__global__ void k_tc(const float* __restrict__ W0, const float* __restrict__ W1,
                     const float* __restrict__ W2, const float* __restrict__ W3,
                     u16* __restrict__ dst) {
  __shared__ float t[64][65];
  const float* W = blockIdx.z == 0 ? W0 : blockIdx.z == 1 ? W1 : blockIdx.z == 2 ? W2 : W3;
  u16* WT = dst + (size_t)blockIdx.z * (1024 * 1024);
  int c0 = blockIdx.x * 64, r0 = blockIdx.y * 64;
  int c = threadIdx.x & 63, q = threadIdx.x >> 6;
  for (int r = q; r < 64; r += 4) t[r][c] = W[(size_t)(r0 + r) * 1024 + c0 + c];
  __syncthreads();
  for (int r = q; r < 64; r += 4) WT[(size_t)(c0 + r) * 1024 + r0 + c] = f2bf(t[c][r]);
}

struct GArgs {
  const u16* A; const u16* B; int lda, ldb; long long bstrideB; int K;
  const float* bias; const float* adj; float* dpart; const float* dpart_r;
  void* C; int ldc;
  const u16* A1; const u16* B1; const u16* B2;
  const float* bias1; const float* bias2; void* C1; void* C2;
};

// 256x256 tile, BK=64, 8 waves (2m x 4n), per-wave C = 128x64 (acc[8][4]).
// LDS 128KB = 2 dbuf x { A[q0 8K][q1 8K] | B[16K] } u16-indexed.
// Row layout: [sr][64 k] with 16B-granule XOR swizzle: u16col = c ^ ((sr&7)<<3).
// A unit q stores sr=0..127 <-> global row (sr>>6)*128 + q*64 + (sr&63).
// Pipeline (fine-WAR, 2 dbuf):
//   ph0(q0,ks0): read B[ks0](4)+Aq0[ks0](4); stage Aq1(u+1)->sbuf; bar;
//                16 MFMA q0; vmcnt(8|0) bar.
//   ph1(q1,ks0): read Aq1[ks0](4); bar; 16 MFMA q1; bar.
//   ph2(q0,ks1): read B[ks1](4)+Aq0[ks1](4); bar; 16 MFMA q0; bar.
//                (B and Aq0 slots now dead)
//   ph3(q1,ks1): read Aq1[ks1](4); stage B(u+2)+Aq0(u+2)->dbuf(!); bar;
//                16 MFMA q1; vmcnt(8|2) bar.
// Issue->use lead = 5 phases; 8 loads in flight across every gate; never
// drains mid-loop. WAR: every stage lands in a slot whose last reader
// phase is >=1 barrier behind.
template <int MODE>
__global__ __launch_bounds__(512, 2) void gemm4(GArgs g) {
  __shared__ __align__(16) u16 sm[65536];  // 128 KB
  __shared__ float dinv[256];

  const int tid = threadIdx.x, lane = tid & 63, wid = tid >> 6;
  const int wm = wid >> 2, wn = wid & 3;

  int bx = blockIdx.x, by = blockIdx.y;
  if constexpr (MODE == M_EXP) {   // XCD chunking: 8bx x 4by per XCD
    int L = bx + (by << 5), xcd = L & 7, j = L >> 3;
    bx = ((xcd & 3) << 3) + (j & 7);
    by = ((xcd >> 2) << 2) + (j >> 3);
  } else if constexpr (MODE == M_PV) {  // 8bx x 2by per XCD
    int L = bx + (by << 5), xcd = L & 7, j = L >> 3;
    bx = ((xcd & 3) << 3) + (j & 7);
    by = ((xcd >> 2) << 1) + (j >> 3);
  }
  const int m0 = bx * 256;
  const int n0 = by * 256;
  const int b = m0 >> 11;  // 2048 rows per batch

  const u16* A = g.A; const u16* B = g.B;
  const float* bias = g.bias; void* C = g.C;
  int zmode = 0;
  if constexpr (MODE == M_PROJ) {
    int z = blockIdx.z; zmode = z;
    if (z == 1) { A = g.A1; B = g.B1; bias = g.bias1; C = g.C1; }
    else if (z == 2) { A = g.A1; B = g.B2; bias = g.bias2; C = g.C2; }
  }
  const int lda = g.lda, ldb = g.ldb, K = g.K, NT = K >> 6;
  const u16* Bp = B + (size_t)b * g.bstrideB;

  f32x4 acc[8][4] = {};

  // ---- staging (512 threads). src col inverse-swizzled, dest linear.
  auto stA = [&](int v, int q, int sb) {   // one A quad: 2 loads/thread
#pragma unroll
    for (int l = 0; l < 2; ++l) {
      int sr = l * 64 + (tid >> 3);
      int grow = m0 + ((sr >> 6) << 7) + (q << 6) + (sr & 63);
      int csrc = ((tid & 7) * 8) ^ ((sr & 7) << 3);
      gload_lds16(A + (size_t)grow * lda + v * 64 + csrc,
                  (void*)&sm[sb + q * 8192 + l * 4096 + tid * 8]);
    }
  };
  auto stB = [&](int v, int h, int sb) {   // one B half: 2 loads/thread
#pragma unroll
    for (int l = 0; l < 2; ++l) {
      int sr = h * 128 + l * 64 + (tid >> 3);
      int csrc = ((tid & 7) * 8) ^ ((sr & 7) << 3);
      gload_lds16(Bp + (size_t)(n0 + sr) * ldb + v * 64 + csrc,
                  (void*)&sm[sb + 16384 + h * 8192 + l * 4096 + tid * 8]);
    }
  };

  // prologue (queue order mimics steady state):
  stB(0, 0, 0); stB(0, 1, 0); stA(0, 0, 0);          // 6: B(0),Aq0(0)
  stA(0, 1, 0);                                      // 2: Aq1(0)
  stB(1, 0, 32768); stB(1, 1, 32768); stA(1, 0, 32768);  // 6: B(1),Aq0(1)
  asm volatile("s_waitcnt vmcnt(8)" ::: "memory");
  __builtin_amdgcn_s_barrier();

  const int fr = lane & 15, hi = lane >> 4;
  const int swz = (fr & 7) << 3;        // u16-col XOR (16B granule)
  const int awb = wm * 64;              // A storage-row base for this wave
  const int bwb = wn * 64;              // B storage-row base

  bf16x8 af[4], bfr[4];

#define RD_A(q, ks)                                                         \
  _Pragma("unroll") for (int m = 0; m < 4; ++m) {                           \
    int sr = awb + m * 16 + fr;                                             \
    af[m] = *(const bf16x8*)__builtin_assume_aligned(                       \
        &sm[dbase + (q) * 8192 + sr * 64 + (((ks) * 32 + hi * 8) ^ swz)], 16); \
  }
#define RD_B(ks)                                                            \
  _Pragma("unroll") for (int n = 0; n < 4; ++n) {                           \
    int sr = bwb + n * 16 + fr;                                             \
    bfr[n] = *(const bf16x8*)__builtin_assume_aligned(                      \
        &sm[dbase + 16384 + sr * 64 + (((ks) * 32 + hi * 8) ^ swz)], 16);   \
  }
#define MFMA_Q(q)                                                           \
  __builtin_amdgcn_s_setprio(1);                                            \
  _Pragma("unroll") for (int m = 0; m < 4; ++m)                             \
  _Pragma("unroll") for (int n = 0; n < 4; ++n)                             \
      acc[(q) * 4 + m][n] = __builtin_amdgcn_mfma_f32_16x16x32_bf16(        \
          af[m], bfr[n], acc[(q) * 4 + m][n], 0, 0, 0);                     \
  __builtin_amdgcn_s_setprio(0);

  for (int u = 0; u < NT; ++u) {
    const int dbase = (u & 1) << 15;
    const int sbase = dbase ^ 32768;

    // ---- ph0 (q0, ks0)
    RD_B(0); RD_A(0, 0);
    if (u + 1 < NT) stA(u + 1, 1, sbase);
    __builtin_amdgcn_s_barrier();
    MFMA_Q(0);
    if (u + 1 < NT) asm volatile("s_waitcnt vmcnt(8)" ::: "memory");
    else            asm volatile("s_waitcnt vmcnt(0)" ::: "memory");
    __builtin_amdgcn_s_barrier();

    // ---- ph1 (q1, ks0)
    RD_A(1, 0);
    __builtin_amdgcn_s_barrier();
    MFMA_Q(1);
    __builtin_amdgcn_s_barrier();

    // ---- ph2 (q0, ks1)
    RD_B(1); RD_A(0, 1);
    __builtin_amdgcn_s_barrier();
    MFMA_Q(0);
    __builtin_amdgcn_s_barrier();

    // ---- ph3 (q1, ks1)
    RD_A(1, 1);
    if (u + 2 < NT) { stB(u + 2, 0, dbase); stB(u + 2, 1, dbase); stA(u + 2, 0, dbase); }
    __builtin_amdgcn_s_barrier();
    MFMA_Q(1);
    if (u + 1 < NT) {
      if (u + 2 < NT) asm volatile("s_waitcnt vmcnt(8)" ::: "memory");
      else            asm volatile("s_waitcnt vmcnt(2)" ::: "memory");
    }
    __builtin_amdgcn_s_barrier();
  }
#undef RD_A
#undef RD_B
#undef MFMA_Q

  // ---- epilogue. C frag: col = lane&15, row = (lane>>4)*4 + r;
  // acc[i]: row-offset = (i>>2)*64 + (i&3)*16 within wave's wm*128 block.
  const int lr = lane >> 4, lc = lane & 15;

  if constexpr (MODE == M_PROJ) {
    if (zmode < 2) {
      u16* Cc = (u16*)C;
#pragma unroll
      for (int i = 0; i < 8; ++i) {
        int rowo = (i >> 2) * 64 + (i & 3) * 16;
#pragma unroll
        for (int n = 0; n < 4; ++n) {
          int gcol = n0 + wn * 64 + n * 16 + lc;
          float bv = bias[gcol];
#pragma unroll
          for (int r = 0; r < 4; ++r) {
            int grow = m0 + wm * 128 + rowo + lr * 4 + r;
            Cc[(size_t)grow * g.ldc + gcol] = f2bf(acc[i][n][r] + bv);
          }
        }
      }
    } else {  // V: store transposed Vt[b][d][t]
      u16* Cc = (u16*)C;
#pragma unroll
      for (int i = 0; i < 8; ++i) {
        int rowo = (i >> 2) * 64 + (i & 3) * 16;
        int grow0 = m0 + wm * 128 + rowo + lr * 4;
        int t0 = grow0 & 2047;
#pragma unroll
        for (int n = 0; n < 4; ++n) {
          int gcol = n0 + wn * 64 + n * 16 + lc;
          float bv = bias[gcol];
          ushort4 pk = make_ushort4(f2bf(acc[i][n][0] + bv), f2bf(acc[i][n][1] + bv),
                                    f2bf(acc[i][n][2] + bv), f2bf(acc[i][n][3] + bv));
          *(ushort4*)&Cc[((size_t)b * 1024 + gcol) * 2048 + t0] = pk;
        }
      }
    }
  } else if constexpr (MODE == M_EXP) {
    u16* Cc = (u16*)C;  // E [8192][2048]
    float esum[8][4];
#pragma unroll
    for (int i = 0; i < 8; ++i)
#pragma unroll
      for (int r = 0; r < 4; ++r) esum[i][r] = 0.f;
#pragma unroll
    for (int i = 0; i < 8; ++i) {
      int rowo = (i >> 2) * 64 + (i & 3) * 16;
#pragma unroll
      for (int n = 0; n < 4; ++n) {
        int gcol = n0 + wn * 64 + n * 16 + lc;
#pragma unroll
        for (int r = 0; r < 4; ++r) {
          int grow = m0 + wm * 128 + rowo + lr * 4 + r;
          float z = acc[i][n][r] * NORM + g.adj[(size_t)grow * 2048 + gcol];
          float e = __expf(z);
          Cc[(size_t)grow * 2048 + gcol] = f2bf(e);
          esum[i][r] += e;
        }
      }
    }
    int pidx = by * 4 + wn;  // 8 t-tiles x 4 wave-cols = 32 partials
#pragma unroll
    for (int i = 0; i < 8; ++i) {
      int rowo = (i >> 2) * 64 + (i & 3) * 16;
#pragma unroll
      for (int r = 0; r < 4; ++r) {
        float s = esum[i][r];
        s += __shfl_xor(s, 1); s += __shfl_xor(s, 2);
        s += __shfl_xor(s, 4); s += __shfl_xor(s, 8);
        if (lc == 0)
          g.dpart[(size_t)pidx * 8192 + m0 + wm * 128 + rowo + lr * 4 + r] = s;
      }
    }
  } else if constexpr (MODE == M_PV) {
    if (tid < 256) {
      float s = 0.f;
#pragma unroll
      for (int t = 0; t < 32; ++t) s += g.dpart_r[(size_t)t * 8192 + m0 + tid];
      dinv[tid] = 1.0f / s;
    }
    __syncthreads();
    u16* Cc = (u16*)C;
#pragma unroll
    for (int i = 0; i < 8; ++i) {
      int rowo = (i >> 2) * 64 + (i & 3) * 16;
#pragma unroll
      for (int n = 0; n < 4; ++n) {
        int gcol = n0 + wn * 64 + n * 16 + lc;
#pragma unroll
        for (int r = 0; r < 4; ++r) {
          int lrow = wm * 128 + rowo + lr * 4 + r;
          Cc[(size_t)(m0 + lrow) * g.ldc + gcol] = f2bf(acc[i][n][r] * dinv[lrow]);
        }
      }
    }
  } else {  // M_OUT: f32 + bias
    float* Cc = (float*)C;
#pragma unroll
    for (int i = 0; i < 8; ++i) {
      int rowo = (i >> 2) * 64 + (i & 3) * 16;
#pragma unroll
      for (int n = 0; n < 4; ++n) {
        int gcol = n0 + wn * 64 + n * 16 + lc;
        float bv = bias[gcol];
#pragma unroll
        for (int r = 0; r < 4; ++r) {
          int grow = m0 + wm * 128 + rowo + lr * 4 + r;
          Cc[(size_t)grow * g.ldc + gcol] = acc[i][n][r] + bv;
        }
      }
    }
  }
}

extern "C" void kernel_launch(void* const* d_in, const int* in_sizes, int n_in,
                              void* d_out, int out_size, void* d_ws, size_t ws_size,
                              hipStream_t stream) {
  const float* x   = (const float*)d_in[0];
  const float* y   = (const float*)d_in[1];
  const float* adj = (const float*)d_in[2];
  const float* Wq  = (const float*)d_in[3];
  const float* bq  = (const float*)d_in[4];
  const float* Wk  = (const float*)d_in[5];
  const float* bk  = (const float*)d_in[6];
  const float* Wv  = (const float*)d_in[7];
  const float* bv  = (const float*)d_in[8];
  const float* Wo  = (const float*)d_in[9];
  const float* bo  = (const float*)d_in[10];
  float* out = (float*)d_out;

  char* ws = (char*)d_ws;
  if (ws_size < 143654912ULL) return;  // need ~137 MB
  u16* xb = (u16*)(ws);                 // [8192][1024] bf16
  u16* yb = (u16*)(ws + 16777216);      // [8192][1024]
  u16* WT = (u16*)(ws + 33554432);      // 4 x [1024][1024] (transposed)
  u16* Qb = (u16*)(ws + 41943040);      // [8192][1024]
  u16* Kb = (u16*)(ws + 58720256);      // [8192][1024]
  u16* Vt = (u16*)(ws + 75497472);      // [4][1024][2048] (V transposed)
  u16* E  = (u16*)(ws + 92274688);      // [8192][2048] unnormalized exp
  float* dpart = (float*)(ws + 125829120);  // [32][8192] partial denoms
  u16* tmpb = (u16*)(ws + 126877696);   // [8192][1024] attention output

  u16* WqT = WT;
  u16* WkT = WT + 1048576;
  u16* WvT = WT + 2097152;
  u16* WoT = WT + 3145728;

  k_cvt<<<8192, 256, 0, stream>>>(x, xb, 2097152);
  k_cvt<<<8192, 256, 0, stream>>>(y, yb, 2097152);
  k_tc<<<dim3(16, 16, 4), 256, 0, stream>>>(Wq, Wk, Wv, Wo, WT);

  GArgs ga;
  // fused Q/K/V projections (z selects); grid 32x4x3 = 384 blocks
  ga.A = xb; ga.B = WqT; ga.lda = 1024; ga.ldb = 1024; ga.bstrideB = 0; ga.K = 1024;
  ga.bias = bq; ga.adj = nullptr; ga.dpart = nullptr; ga.dpart_r = nullptr;
  ga.C = Qb; ga.ldc = 1024;
  ga.A1 = yb; ga.B1 = WkT; ga.B2 = WvT; ga.bias1 = bk; ga.bias2 = bv;
  ga.C1 = Kb; ga.C2 = Vt;
  gemm4<M_PROJ><<<dim3(32, 4, 3), 512, 0, stream>>>(ga);

  // E = exp(Q@K^T * norm + adj), partial row sums; 32x8 = 256 = 1 round
  GArgs ge = {};
  ge.A = Qb; ge.B = Kb; ge.lda = 1024; ge.ldb = 1024; ge.bstrideB = 2097152LL; ge.K = 1024;
  ge.bias = nullptr; ge.adj = adj; ge.dpart = dpart; ge.dpart_r = nullptr;
  ge.C = E; ge.ldc = 2048;
  gemm4<M_EXP><<<dim3(32, 8), 512, 0, stream>>>(ge);

  // tmp = (E @ V) / denom; 32x4 = 128 blocks
  GArgs gp = {};
  gp.A = E; gp.B = Vt; gp.lda = 2048; gp.ldb = 2048; gp.bstrideB = 2097152LL; gp.K = 2048;
  gp.bias = nullptr; gp.adj = nullptr; gp.dpart = nullptr; gp.dpart_r = dpart;
  gp.C = tmpb; gp.ldc = 1024;
  gemm4<M_PV><<<dim3(32, 4), 512, 0, stream>>>(gp);

  // out = tmp @ Wo + bo  (f32); 128 blocks
  GArgs go = {};
  go.A = tmpb; go.B = WoT; go.lda = 1024; go.ldb = 1024; go.bstrideB = 0; go.K = 1024;
  go.bias = bo; go.adj = nullptr; go.dpart = nullptr; go.dpart_r = nullptr;
  go.C = out; go.ldc = 1024;
  gemm4<M_OUT><<<dim3(32, 4), 512, 0, stream>>>(go);
}

// Round 7
// 225.955 us; speedup vs baseline: 1.2170x; 1.2170x over previous
//
#include <hip/hip_runtime.h>
#include <stdint.h>

typedef unsigned short u16;
using bf16x8 = __attribute__((ext_vector_type(8))) short;
using f32x4  = __attribute__((ext_vector_type(4))) float;

#define NORM 0.03125f  // 1/sqrt(1024)

enum { M_PROJ = 0, M_EXP = 1, M_PV = 2, M_OUT = 3 };

__device__ __forceinline__ u16 f2bf(float f) {
  uint32_t u = __float_as_uint(f);
  return (u16)((u + 0x7FFFu + ((u >> 16) & 1u)) >> 16);  // RNE
}

__device__ __forceinline__ void gload_lds16(const void* g, void* lds) {
  __builtin_amdgcn_global_load_lds(
      (const __attribute__((address_space(1))) uint32_t*)g,
      (__attribute__((address_space(3))) uint32_t*)lds, 16, 0, 0);
}

// compiler-invisible LDS read: hardware ds_read_b128 at (32-bit LDS byte
// address) + literal offset. Generic pointers to __shared__ carry the LDS
// byte offset in their low 32 bits on AMDGCN.
#define DSR(dst, base, off)                                        \
  asm volatile("ds_read_b128 %0, %1 offset:" #off                  \
               : "=v"(dst) : "v"(base))

// f32 -> bf16 elementwise, 4 elems/thread
__global__ void k_cvt(const float* __restrict__ in, u16* __restrict__ out, int n4) {
  int i = blockIdx.x * blockDim.x + threadIdx.x;
  if (i >= n4) return;
  float4 v = ((const float4*)in)[i];
  uint32_t lo = f2bf(v.x) | ((uint32_t)f2bf(v.y) << 16);
  uint32_t hi = f2bf(v.z) | ((uint32_t)f2bf(v.w) << 16);
  ((uint2*)out)[i] = make_uint2(lo, hi);
}

// transpose + convert the 4 weight matrices [1024x1024] f32 -> WT[n][k] bf16
__global__ void k_tc(const float* __restrict__ W0, const float* __restrict__ W1,
                     const float* __restrict__ W2, const float* __restrict__ W3,
                     u16* __restrict__ dst) {
  __shared__ float t[64][65];
  const float* W = blockIdx.z == 0 ? W0 : blockIdx.z == 1 ? W1 : blockIdx.z == 2 ? W2 : W3;
  u16* WT = dst + (size_t)blockIdx.z * (1024 * 1024);
  int c0 = blockIdx.x * 64, r0 = blockIdx.y * 64;
  int c = threadIdx.x & 63, q = threadIdx.x >> 6;
  for (int r = q; r < 64; r += 4) t[r][c] = W[(size_t)(r0 + r) * 1024 + c0 + c];
  __syncthreads();
  for (int r = q; r < 64; r += 4) WT[(size_t)(c0 + r) * 1024 + r0 + c] = f2bf(t[c][r]);
}

struct GArgs {
  const u16* A; const u16* B; int lda, ldb; long long bstrideB; int K;
  const float* bias; const float* adj; float* dpart; const float* dpart_r;
  void* C; int ldc;
  const u16* A1; const u16* B1; const u16* B2;
  const float* bias1; const float* bias2; void* C1; void* C2;
};

// 128(M) x 256(N) tile, BK=64, 8 waves (2m x 4n), per-wave C = 64x64.
// LDS: 3 buffers x { A[2kh][128][32] | B[2kh][256][32] } bf16 = 144 KB.
// st_16x32 swizzle: phys_byte = row*64 + (cb ^ ((row&8)<<2)); staged with
// linear LDS dest + inverse-swizzled global source (involution).
// Schedule: fragment loads are INLINE-ASM ds_read_b128 (compiler-invisible,
// so the compiler cannot insert conservative vmcnt(0) drains against the
// outstanding global_load_lds queue). Per phase:
//   {8 asm ds_read | stage issue | s_barrier | lgkmcnt(0)+sched_barrier(0)
//    | setprio1 16 MFMA setprio0 | s_barrier}
// Counted vmcnt(6) ONCE per K-tile (before the closing barrier): during
// tile u we stage tile u+2 (6 loads); at the wait, outstanding = tiles
// u+1,u+2 (12) -> vmcnt(6) leaves exactly tile u+1 in flight. Drain to 0
// only entering the last tile. RAW: tile u's data was staged 2 closing
// barriers ago and covered by the previous tile's vmcnt(6). WAR: stages
// write buf[(u+2)%3], whose last readers (tile u-1) completed their
// lgkmcnt(0) before tile u-1's closing barrier.
template <int MODE>
__global__ __launch_bounds__(512, 2) void gemm3(GArgs g) {
  __shared__ __align__(16) u16 sm[73728];  // 144 KB

  const int tid = threadIdx.x, lane = tid & 63, wid = tid >> 6;
  const int wm = wid >> 2, wn = wid & 3;
  const int m0 = blockIdx.x * 128;
  const int n0 = blockIdx.y * 256;
  const int b = m0 >> 11;  // 2048 rows per batch

  const u16* A = g.A; const u16* B = g.B;
  const float* bias = g.bias; void* C = g.C;
  int zmode = 0;
  if constexpr (MODE == M_PROJ) {
    int z = blockIdx.z; zmode = z;
    if (z == 1) { A = g.A1; B = g.B1; bias = g.bias1; C = g.C1; }
    else if (z == 2) { A = g.A1; B = g.B2; bias = g.bias2; C = g.C2; }
  }
  const int lda = g.lda, ldb = g.ldb, K = g.K, NT = K >> 6;
  const u16* Bp = B + (size_t)b * g.bstrideB;

  f32x4 acc[4][4] = {};

  const int srow = tid >> 2;           // staging row 0..127
  const int scb = (tid & 3) * 16;      // staging col-byte 0..48
  // stage one (A,kh) unit: 128x32 bf16 = 8KB, 1 load/thread
  auto stageA = [&](int v, int kh, int bufb) {
    int csw = scb ^ ((srow & 8) << 2);
    gload_lds16(A + (size_t)(m0 + srow) * lda + v * 64 + kh * 32 + (csw >> 1),
                (void*)&sm[bufb + kh * 4096 + srow * 32 + (tid & 3) * 8]);
  };
  // stage one (B,kh) unit: 256x32 bf16 = 16KB, 2 loads/thread
  auto stageB = [&](int v, int kh, int bufb) {
#pragma unroll
    for (int j = 0; j < 2; ++j) {
      int row = j * 128 + srow;
      int csw = scb ^ ((row & 8) << 2);
      gload_lds16(Bp + (size_t)(n0 + row) * ldb + v * 64 + kh * 32 + (csw >> 1),
                  (void*)&sm[bufb + 8192 + kh * 8192 + row * 32 + (tid & 3) * 8]);
    }
  };

  // prologue: stage tiles 0 and 1 (12 loads/thread total)
  stageA(0, 0, 0);     stageB(0, 0, 0);
  stageA(0, 1, 0);     stageB(0, 1, 0);
  stageA(1, 0, 24576); stageB(1, 0, 24576);
  stageA(1, 1, 24576); stageB(1, 1, 24576);
  asm volatile("s_waitcnt vmcnt(6)" ::: "memory");  // tile 0 resident
  __builtin_amdgcn_s_barrier();

  // fragment-read base addresses (32-bit LDS byte addresses)
  const uint32_t smu = (uint32_t)(uintptr_t)&sm[0];
  const int fr = lane & 15;
  const int swz = ((lane >> 4) * 16) ^ ((fr & 8) << 2);  // byte, row-invariant
  const uint32_t arow = (uint32_t)((wm * 64 + fr) * 64 + swz);
  const uint32_t brow = (uint32_t)(16384 + (wn * 64 + fr) * 64 + swz);

  bf16x8 a0, a1, a2, a3, b0, b1, b2, b3;

#define MFMA16()                                                            \
  __builtin_amdgcn_s_setprio(1);                                            \
  acc[0][0] = __builtin_amdgcn_mfma_f32_16x16x32_bf16(a0, b0, acc[0][0], 0, 0, 0); \
  acc[0][1] = __builtin_amdgcn_mfma_f32_16x16x32_bf16(a0, b1, acc[0][1], 0, 0, 0); \
  acc[0][2] = __builtin_amdgcn_mfma_f32_16x16x32_bf16(a0, b2, acc[0][2], 0, 0, 0); \
  acc[0][3] = __builtin_amdgcn_mfma_f32_16x16x32_bf16(a0, b3, acc[0][3], 0, 0, 0); \
  acc[1][0] = __builtin_amdgcn_mfma_f32_16x16x32_bf16(a1, b0, acc[1][0], 0, 0, 0); \
  acc[1][1] = __builtin_amdgcn_mfma_f32_16x16x32_bf16(a1, b1, acc[1][1], 0, 0, 0); \
  acc[1][2] = __builtin_amdgcn_mfma_f32_16x16x32_bf16(a1, b2, acc[1][2], 0, 0, 0); \
  acc[1][3] = __builtin_amdgcn_mfma_f32_16x16x32_bf16(a1, b3, acc[1][3], 0, 0, 0); \
  acc[2][0] = __builtin_amdgcn_mfma_f32_16x16x32_bf16(a2, b0, acc[2][0], 0, 0, 0); \
  acc[2][1] = __builtin_amdgcn_mfma_f32_16x16x32_bf16(a2, b1, acc[2][1], 0, 0, 0); \
  acc[2][2] = __builtin_amdgcn_mfma_f32_16x16x32_bf16(a2, b2, acc[2][2], 0, 0, 0); \
  acc[2][3] = __builtin_amdgcn_mfma_f32_16x16x32_bf16(a2, b3, acc[2][3], 0, 0, 0); \
  acc[3][0] = __builtin_amdgcn_mfma_f32_16x16x32_bf16(a3, b0, acc[3][0], 0, 0, 0); \
  acc[3][1] = __builtin_amdgcn_mfma_f32_16x16x32_bf16(a3, b1, acc[3][1], 0, 0, 0); \
  acc[3][2] = __builtin_amdgcn_mfma_f32_16x16x32_bf16(a3, b2, acc[3][2], 0, 0, 0); \
  acc[3][3] = __builtin_amdgcn_mfma_f32_16x16x32_bf16(a3, b3, acc[3][3], 0, 0, 0); \
  __builtin_amdgcn_s_setprio(0);

  int rd = 0;
  for (int u = 0; u < NT; ++u) {
    const uint32_t bb = smu + (uint32_t)rd * 49152u;
    const uint32_t abase = bb + arow;
    const uint32_t bbase = bb + brow;
    const int stb = (rd == 0 ? 2 : rd - 1) * 24576;  // buffer of tile u+2

    // ---------- phase 1 (kh = 0) ----------
    DSR(a0, abase, 0);    DSR(a1, abase, 1024);
    DSR(a2, abase, 2048); DSR(a3, abase, 3072);
    DSR(b0, bbase, 0);    DSR(b1, bbase, 1024);
    DSR(b2, bbase, 2048); DSR(b3, bbase, 3072);
    if (u + 2 < NT) { stageA(u + 2, 0, stb); stageA(u + 2, 1, stb); }
    __builtin_amdgcn_s_barrier();
    asm volatile("s_waitcnt lgkmcnt(0)" ::: "memory");
    __builtin_amdgcn_sched_barrier(0);  // rule #18: pin MFMA after the wait
    MFMA16();
    __builtin_amdgcn_s_barrier();

    // ---------- phase 2 (kh = 1) ----------
    DSR(a0, abase, 8192);  DSR(a1, abase, 9216);
    DSR(a2, abase, 10240); DSR(a3, abase, 11264);
    DSR(b0, bbase, 16384); DSR(b1, bbase, 17408);
    DSR(b2, bbase, 18432); DSR(b3, bbase, 19456);
    if (u + 2 < NT) { stageB(u + 2, 0, stb); stageB(u + 2, 1, stb); }
    __builtin_amdgcn_s_barrier();
    asm volatile("s_waitcnt lgkmcnt(0)" ::: "memory");
    __builtin_amdgcn_sched_barrier(0);
    MFMA16();
    // tile-boundary counted wait: next tile's reads need tile u+1 resident
    if (u + 2 < NT)      asm volatile("s_waitcnt vmcnt(6)" ::: "memory");
    else if (u + 1 < NT) asm volatile("s_waitcnt vmcnt(0)" ::: "memory");
    __builtin_amdgcn_s_barrier();

    rd = (rd == 2) ? 0 : rd + 1;
  }
#undef MFMA16

  // ---- epilogue. C frag layout: col = lane&15, row = (lane>>4)*4 + r
  const int lr = lane >> 4, lc = lane & 15;

  if constexpr (MODE == M_PROJ) {
    if (zmode < 2) {
      u16* Cc = (u16*)C;
#pragma unroll
      for (int m = 0; m < 4; ++m)
#pragma unroll
        for (int n = 0; n < 4; ++n) {
          int gcol = n0 + wn * 64 + n * 16 + lc;
          float bv = bias[gcol];
#pragma unroll
          for (int r = 0; r < 4; ++r) {
            int grow = m0 + wm * 64 + m * 16 + lr * 4 + r;
            Cc[(size_t)grow * g.ldc + gcol] = f2bf(acc[m][n][r] + bv);
          }
        }
    } else {  // V: store transposed Vt[b][d][t]
      u16* Cc = (u16*)C;
#pragma unroll
      for (int m = 0; m < 4; ++m) {
        int grow0 = m0 + wm * 64 + m * 16 + lr * 4;
        int t0 = grow0 & 2047;
#pragma unroll
        for (int n = 0; n < 4; ++n) {
          int gcol = n0 + wn * 64 + n * 16 + lc;
          float bv = bias[gcol];
          ushort4 pk = make_ushort4(f2bf(acc[m][n][0] + bv), f2bf(acc[m][n][1] + bv),
                                    f2bf(acc[m][n][2] + bv), f2bf(acc[m][n][3] + bv));
          *(ushort4*)&Cc[((size_t)b * 1024 + gcol) * 2048 + t0] = pk;
        }
      }
    }
  } else if constexpr (MODE == M_EXP) {
    u16* Cc = (u16*)C;  // E [8192][2048]
    float esum[4][4];
#pragma unroll
    for (int m = 0; m < 4; ++m)
#pragma unroll
      for (int r = 0; r < 4; ++r) esum[m][r] = 0.f;
#pragma unroll
    for (int m = 0; m < 4; ++m)
#pragma unroll
      for (int n = 0; n < 4; ++n) {
        int gcol = n0 + wn * 64 + n * 16 + lc;
#pragma unroll
        for (int r = 0; r < 4; ++r) {
          int grow = m0 + wm * 64 + m * 16 + lr * 4 + r;
          float z = acc[m][n][r] * NORM + g.adj[(size_t)grow * 2048 + gcol];
          float e = __expf(z);
          Cc[(size_t)grow * 2048 + gcol] = f2bf(e);
          esum[m][r] += e;
        }
      }
    int pidx = blockIdx.y * 4 + wn;  // 8 t-tiles x 4 wave-cols = 32 partials
#pragma unroll
    for (int m = 0; m < 4; ++m)
#pragma unroll
      for (int r = 0; r < 4; ++r) {
        float s = esum[m][r];
        s += __shfl_xor(s, 1); s += __shfl_xor(s, 2);
        s += __shfl_xor(s, 4); s += __shfl_xor(s, 8);
        if (lc == 0)
          g.dpart[(size_t)pidx * 8192 + m0 + wm * 64 + m * 16 + lr * 4 + r] = s;
      }
  } else if constexpr (MODE == M_PV) {
    __shared__ float dinv[128];
    if (tid < 128) {
      float s = 0.f;
#pragma unroll
      for (int t = 0; t < 32; ++t) s += g.dpart_r[(size_t)t * 8192 + m0 + tid];
      dinv[tid] = 1.0f / s;
    }
    __syncthreads();
    u16* Cc = (u16*)C;
#pragma unroll
    for (int m = 0; m < 4; ++m)
#pragma unroll
      for (int n = 0; n < 4; ++n) {
        int gcol = n0 + wn * 64 + n * 16 + lc;
#pragma unroll
        for (int r = 0; r < 4; ++r) {
          int lrow = wm * 64 + m * 16 + lr * 4 + r;
          Cc[(size_t)(m0 + lrow) * g.ldc + gcol] = f2bf(acc[m][n][r] * dinv[lrow]);
        }
      }
  } else {  // M_OUT: f32 + bias
    float* Cc = (float*)C;
#pragma unroll
    for (int m = 0; m < 4; ++m)
#pragma unroll
      for (int n = 0; n < 4; ++n) {
        int gcol = n0 + wn * 64 + n * 16 + lc;
        float bv = bias[gcol];
#pragma unroll
        for (int r = 0; r < 4; ++r) {
          int grow = m0 + wm * 64 + m * 16 + lr * 4 + r;
          Cc[(size_t)grow * g.ldc + gcol] = acc[m][n][r] + bv;
        }
      }
  }
}

extern "C" void kernel_launch(void* const* d_in, const int* in_sizes, int n_in,
                              void* d_out, int out_size, void* d_ws, size_t ws_size,
                              hipStream_t stream) {
  const float* x   = (const float*)d_in[0];
  const float* y   = (const float*)d_in[1];
  const float* adj = (const float*)d_in[2];
  const float* Wq  = (const float*)d_in[3];
  const float* bq  = (const float*)d_in[4];
  const float* Wk  = (const float*)d_in[5];
  const float* bk  = (const float*)d_in[6];
  const float* Wv  = (const float*)d_in[7];
  const float* bv  = (const float*)d_in[8];
  const float* Wo  = (const float*)d_in[9];
  const float* bo  = (const float*)d_in[10];
  float* out = (float*)d_out;

  char* ws = (char*)d_ws;
  if (ws_size < 143654912ULL) return;  // need ~137 MB
  u16* xb = (u16*)(ws);                 // [8192][1024] bf16
  u16* yb = (u16*)(ws + 16777216);      // [8192][1024]
  u16* WT = (u16*)(ws + 33554432);      // 4 x [1024][1024] (transposed)
  u16* Qb = (u16*)(ws + 41943040);      // [8192][1024]
  u16* Kb = (u16*)(ws + 58720256);      // [8192][1024]
  u16* Vt = (u16*)(ws + 75497472);      // [4][1024][2048] (V transposed)
  u16* E  = (u16*)(ws + 92274688);      // [8192][2048] unnormalized exp
  float* dpart = (float*)(ws + 125829120);  // [32][8192] partial denoms
  u16* tmpb = (u16*)(ws + 126877696);   // [8192][1024] attention output

  u16* WqT = WT;
  u16* WkT = WT + 1048576;
  u16* WvT = WT + 2097152;
  u16* WoT = WT + 3145728;

  k_cvt<<<8192, 256, 0, stream>>>(x, xb, 2097152);
  k_cvt<<<8192, 256, 0, stream>>>(y, yb, 2097152);
  k_tc<<<dim3(16, 16, 4), 256, 0, stream>>>(Wq, Wk, Wv, Wo, WT);

  GArgs ga;
  // fused Q/K/V projections (z selects); grid 64x4x3 = 768 = 3 full rounds
  ga.A = xb; ga.B = WqT; ga.lda = 1024; ga.ldb = 1024; ga.bstrideB = 0; ga.K = 1024;
  ga.bias = bq; ga.adj = nullptr; ga.dpart = nullptr; ga.dpart_r = nullptr;
  ga.C = Qb; ga.ldc = 1024;
  ga.A1 = yb; ga.B1 = WkT; ga.B2 = WvT; ga.bias1 = bk; ga.bias2 = bv;
  ga.C1 = Kb; ga.C2 = Vt;
  gemm3<M_PROJ><<<dim3(64, 4, 3), 512, 0, stream>>>(ga);

  // E = exp(Q@K^T * norm + adj), partial row sums; 64x8 = 512 = 2 rounds
  GArgs ge = {};
  ge.A = Qb; ge.B = Kb; ge.lda = 1024; ge.ldb = 1024; ge.bstrideB = 2097152LL; ge.K = 1024;
  ge.bias = nullptr; ge.adj = adj; ge.dpart = dpart; ge.dpart_r = nullptr;
  ge.C = E; ge.ldc = 2048;
  gemm3<M_EXP><<<dim3(64, 8), 512, 0, stream>>>(ge);

  // tmp = (E @ V) / denom; 64x4 = 256 = 1 full round
  GArgs gp = {};
  gp.A = E; gp.B = Vt; gp.lda = 2048; gp.ldb = 2048; gp.bstrideB = 2097152LL; gp.K = 2048;
  gp.bias = nullptr; gp.adj = nullptr; gp.dpart = nullptr; gp.dpart_r = dpart;
  gp.C = tmpb; gp.ldc = 1024;
  gemm3<M_PV><<<dim3(64, 4), 512, 0, stream>>>(gp);

  // out = tmp @ Wo + bo  (f32); 256 blocks = 1 round
  GArgs go = {};
  go.A = tmpb; go.B = WoT; go.lda = 1024; go.ldb = 1024; go.bstrideB = 0; go.K = 1024;
  go.bias = bo; go.adj = nullptr; go.dpart = nullptr; go.dpart_r = nullptr;
  go.C = out; go.ldc = 1024;
  gemm3<M_OUT><<<dim3(64, 4), 512, 0, stream>>>(go);
}

// Round 8
// 219.006 us; speedup vs baseline: 1.2556x; 1.0317x over previous
//
#include <hip/hip_runtime.h>
#include <stdint.h>

typedef unsigned short u16;
using bf16x8 = __attribute__((ext_vector_type(8))) short;
using f32x4  = __attribute__((ext_vector_type(4))) float;

#define NORM 0.03125f  // 1/sqrt(1024)

enum { M_PROJ = 0, M_EXP = 1, M_PV = 2, M_OUT = 3 };

__device__ __forceinline__ u16 f2bf(float f) {
  uint32_t u = __float_as_uint(f);
  return (u16)((u + 0x7FFFu + ((u >> 16) & 1u)) >> 16);  // RNE
}

__device__ __forceinline__ void gload_lds16(const void* g, void* lds) {
  __builtin_amdgcn_global_load_lds(
      (const __attribute__((address_space(1))) uint32_t*)g,
      (__attribute__((address_space(3))) uint32_t*)lds, 16, 0, 0);
}

// f32 -> bf16 elementwise, 4 elems/thread
__global__ void k_cvt(const float* __restrict__ in, u16* __restrict__ out, int n4) {
  int i = blockIdx.x * blockDim.x + threadIdx.x;
  if (i >= n4) return;
  float4 v = ((const float4*)in)[i];
  uint32_t lo = f2bf(v.x) | ((uint32_t)f2bf(v.y) << 16);
  uint32_t hi = f2bf(v.z) | ((uint32_t)f2bf(v.w) << 16);
  ((uint2*)out)[i] = make_uint2(lo, hi);
}

// transpose + convert the 4 weight matrices [1024x1024] f32 -> WT[n][k] bf16
__global__ void k_tc(const float* __restrict__ W0, const float* __restrict__ W1,
                     const float* __restrict__ W2, const float* __restrict__ W3,
                     u16* __restrict__ dst) {
  __shared__ float t[64][65];
  const float* W = blockIdx.z == 0 ? W0 : blockIdx.z == 1 ? W1 : blockIdx.z == 2 ? W2 : W3;
  u16* WT = dst + (size_t)blockIdx.z * (1024 * 1024);
  int c0 = blockIdx.x * 64, r0 = blockIdx.y * 64;
  int c = threadIdx.x & 63, q = threadIdx.x >> 6;
  for (int r = q; r < 64; r += 4) t[r][c] = W[(size_t)(r0 + r) * 1024 + c0 + c];
  __syncthreads();
  for (int r = q; r < 64; r += 4) WT[(size_t)(c0 + r) * 1024 + r0 + c] = f2bf(t[c][r]);
}

struct GArgs {
  const u16* A; const u16* B; int lda, ldb; long long bstrideB; int K;
  const float* bias; const float* adj; float* dpart; const float* dpart_r;
  void* C; int ldc;
  const u16* A1; const u16* B1; const u16* B2;
  const float* bias1; const float* bias2; void* C1; void* C2;
};

// m97 structure, occupancy-first: 128x128 tile, BK=64, 4 waves (2x2),
// per-wave 64x64 (4x4 16x16x32 MFMA). LDS 32KB single-buffered ->
// 4 blocks/CU resident (VGPR<=128 via launch_bounds(256,4)); latency is
// hidden by INTER-BLOCK overlap (m114), not intra-block pipelining.
// LDS tiles [128][64] u16 with XOR swizzle: phys_u16col = c ^ ((row&7)<<3)
// (16B granules). Staged via linear gload_lds dest + inverse-swizzled
// global source column; reads apply the same XOR -> <=2-way conflicts.
template <int MODE>
__global__ __launch_bounds__(256, 4) void gemm_occ(GArgs g) {
  __shared__ __align__(16) u16 As[128 * 64];
  __shared__ __align__(16) u16 Bs[128 * 64];

  const int tid = threadIdx.x;
  const int lane = tid & 63;
  const int wid = tid >> 6;
  const int wr = wid >> 1, wc = wid & 1;

  const int m0 = blockIdx.x * 128;
  const int n0 = blockIdx.y * 128;
  const int b = m0 >> 11;  // 2048 rows per batch

  const u16* A = g.A; const u16* B = g.B;
  const float* bias = g.bias; void* C = g.C;
  int zmode = 0;
  if constexpr (MODE == M_PROJ) {
    int z = blockIdx.z; zmode = z;
    if (z == 1) { A = g.A1; B = g.B1; bias = g.bias1; C = g.C1; }
    else if (z == 2) { A = g.A1; B = g.B2; bias = g.bias2; C = g.C2; }
  }
  const int lda = g.lda, ldb = g.ldb, K = g.K;
  const u16* Bp = B + (size_t)b * g.bstrideB;

  f32x4 acc[4][4] = {};

  const int ric = lane >> 3;         // row within 8-row chunk
  const int c8 = (lane & 7) * 8;     // u16 col granule (16B)

  const int fr = lane & 15;
  const int hi = lane >> 4;

  for (int kt = 0; kt < K; kt += 64) {
#pragma unroll
    for (int c = 0; c < 4; ++c) {
      int ch = wid * 4 + c;          // 16 chunks of 8 rows x 128B
      int row = ch * 8 + ric;
      int swc = c8 ^ ((row & 7) << 3);  // inverse-swizzled source col
      gload_lds16(A + (size_t)(m0 + row) * lda + kt + swc, (void*)&As[ch * 512]);
      gload_lds16(Bp + (size_t)(n0 + row) * ldb + kt + swc, (void*)&Bs[ch * 512]);
    }
    __syncthreads();
#pragma unroll
    for (int kk = 0; kk < 64; kk += 32) {
      bf16x8 af[4], bfr[4];
#pragma unroll
      for (int m = 0; m < 4; ++m) {
        int row = wr * 64 + m * 16 + fr;
        af[m] = *(const bf16x8*)__builtin_assume_aligned(
            &As[row * 64 + ((kk + hi * 8) ^ ((row & 7) << 3))], 16);
      }
#pragma unroll
      for (int n = 0; n < 4; ++n) {
        int row = wc * 64 + n * 16 + fr;
        bfr[n] = *(const bf16x8*)__builtin_assume_aligned(
            &Bs[row * 64 + ((kk + hi * 8) ^ ((row & 7) << 3))], 16);
      }
#pragma unroll
      for (int m = 0; m < 4; ++m)
#pragma unroll
        for (int n = 0; n < 4; ++n)
          acc[m][n] = __builtin_amdgcn_mfma_f32_16x16x32_bf16(af[m], bfr[n], acc[m][n], 0, 0, 0);
    }
    __syncthreads();
  }

  // C layout (m89-verified): col = lane&15, row = (lane>>4)*4 + reg
  const int lr = lane >> 4;
  const int lc = lane & 15;

  if constexpr (MODE == M_PROJ) {
    if (zmode < 2) {
      u16* Cc = (u16*)C;
#pragma unroll
      for (int m = 0; m < 4; ++m)
#pragma unroll
        for (int n = 0; n < 4; ++n) {
          int gcol = n0 + wc * 64 + n * 16 + lc;
          float bv = bias[gcol];
#pragma unroll
          for (int r = 0; r < 4; ++r) {
            int grow = m0 + wr * 64 + m * 16 + lr * 4 + r;
            Cc[(size_t)grow * g.ldc + gcol] = f2bf(acc[m][n][r] + bv);
          }
        }
    } else {  // V: store transposed Vt[b][d][t]
      u16* Cc = (u16*)C;
#pragma unroll
      for (int m = 0; m < 4; ++m) {
        int grow0 = m0 + wr * 64 + m * 16 + lr * 4;
        int t0 = grow0 & 2047;
#pragma unroll
        for (int n = 0; n < 4; ++n) {
          int gcol = n0 + wc * 64 + n * 16 + lc;
          float bv = bias[gcol];
          ushort4 pk = make_ushort4(f2bf(acc[m][n][0] + bv), f2bf(acc[m][n][1] + bv),
                                    f2bf(acc[m][n][2] + bv), f2bf(acc[m][n][3] + bv));
          *(ushort4*)&Cc[((size_t)b * 1024 + gcol) * 2048 + t0] = pk;
        }
      }
    }
  } else if constexpr (MODE == M_EXP) {
    u16* Cc = (u16*)C;  // E [8192][2048]
    float esum[4][4] = {};
#pragma unroll
    for (int m = 0; m < 4; ++m)
#pragma unroll
      for (int n = 0; n < 4; ++n) {
        int gcol = n0 + wc * 64 + n * 16 + lc;
#pragma unroll
        for (int r = 0; r < 4; ++r) {
          int grow = m0 + wr * 64 + m * 16 + lr * 4 + r;
          float z = acc[m][n][r] * NORM + g.adj[(size_t)grow * 2048 + gcol];
          float e = __expf(z);
          Cc[(size_t)grow * 2048 + gcol] = f2bf(e);
          esum[m][r] += e;
        }
      }
    int pidx = blockIdx.y * 2 + wc;  // 16 t-tiles x 2 wave-cols = 32 partials
#pragma unroll
    for (int m = 0; m < 4; ++m)
#pragma unroll
      for (int r = 0; r < 4; ++r) {
        float s = esum[m][r];
        s += __shfl_xor(s, 1); s += __shfl_xor(s, 2);
        s += __shfl_xor(s, 4); s += __shfl_xor(s, 8);
        if (lc == 0)
          g.dpart[(size_t)pidx * 8192 + (m0 + wr * 64 + m * 16 + lr * 4 + r)] = s;
      }
  } else if constexpr (MODE == M_PV) {
    __shared__ float dinv[128];
    if (tid < 128) {
      float s = 0.f;
#pragma unroll
      for (int t = 0; t < 32; ++t) s += g.dpart_r[(size_t)t * 8192 + m0 + tid];
      dinv[tid] = 1.0f / s;
    }
    __syncthreads();
    u16* Cc = (u16*)C;
#pragma unroll
    for (int m = 0; m < 4; ++m)
#pragma unroll
      for (int n = 0; n < 4; ++n) {
        int gcol = n0 + wc * 64 + n * 16 + lc;
#pragma unroll
        for (int r = 0; r < 4; ++r) {
          int lrow = wr * 64 + m * 16 + lr * 4 + r;
          Cc[(size_t)(m0 + lrow) * g.ldc + gcol] = f2bf(acc[m][n][r] * dinv[lrow]);
        }
      }
  } else {  // M_OUT: f32 + bias
    float* Cc = (float*)C;
#pragma unroll
    for (int m = 0; m < 4; ++m)
#pragma unroll
      for (int n = 0; n < 4; ++n) {
        int gcol = n0 + wc * 64 + n * 16 + lc;
        float bv = bias[gcol];
#pragma unroll
        for (int r = 0; r < 4; ++r) {
          int grow = m0 + wr * 64 + m * 16 + lr * 4 + r;
          Cc[(size_t)grow * g.ldc + gcol] = acc[m][n][r] + bv;
        }
      }
  }
}

extern "C" void kernel_launch(void* const* d_in, const int* in_sizes, int n_in,
                              void* d_out, int out_size, void* d_ws, size_t ws_size,
                              hipStream_t stream) {
  const float* x   = (const float*)d_in[0];
  const float* y   = (const float*)d_in[1];
  const float* adj = (const float*)d_in[2];
  const float* Wq  = (const float*)d_in[3];
  const float* bq  = (const float*)d_in[4];
  const float* Wk  = (const float*)d_in[5];
  const float* bk  = (const float*)d_in[6];
  const float* Wv  = (const float*)d_in[7];
  const float* bv  = (const float*)d_in[8];
  const float* Wo  = (const float*)d_in[9];
  const float* bo  = (const float*)d_in[10];
  float* out = (float*)d_out;

  char* ws = (char*)d_ws;
  if (ws_size < 143654912ULL) return;  // need ~137 MB
  u16* xb = (u16*)(ws);                 // [8192][1024] bf16
  u16* yb = (u16*)(ws + 16777216);      // [8192][1024]
  u16* WT = (u16*)(ws + 33554432);      // 4 x [1024][1024] (transposed)
  u16* Qb = (u16*)(ws + 41943040);      // [8192][1024]
  u16* Kb = (u16*)(ws + 58720256);      // [8192][1024]
  u16* Vt = (u16*)(ws + 75497472);      // [4][1024][2048] (V transposed)
  u16* E  = (u16*)(ws + 92274688);      // [8192][2048] unnormalized exp
  float* dpart = (float*)(ws + 125829120);  // [32][8192] partial denoms
  u16* tmpb = (u16*)(ws + 126877696);   // [8192][1024] attention output

  u16* WqT = WT;
  u16* WkT = WT + 1048576;
  u16* WvT = WT + 2097152;
  u16* WoT = WT + 3145728;

  k_cvt<<<8192, 256, 0, stream>>>(x, xb, 2097152);
  k_cvt<<<8192, 256, 0, stream>>>(y, yb, 2097152);
  k_tc<<<dim3(16, 16, 4), 256, 0, stream>>>(Wq, Wk, Wv, Wo, WT);

  GArgs ga;
  // fused Q/K/V projections (z selects); 64x8x3 = 1536 blocks -> ~6/CU queued
  ga.A = xb; ga.B = WqT; ga.lda = 1024; ga.ldb = 1024; ga.bstrideB = 0; ga.K = 1024;
  ga.bias = bq; ga.adj = nullptr; ga.dpart = nullptr; ga.dpart_r = nullptr;
  ga.C = Qb; ga.ldc = 1024;
  ga.A1 = yb; ga.B1 = WkT; ga.B2 = WvT; ga.bias1 = bk; ga.bias2 = bv;
  ga.C1 = Kb; ga.C2 = Vt;
  gemm_occ<M_PROJ><<<dim3(64, 8, 3), 256, 0, stream>>>(ga);

  // E = exp(Q@K^T * norm + adj), partial row sums; 64x16 = 1024 blocks
  GArgs ge = {};
  ge.A = Qb; ge.B = Kb; ge.lda = 1024; ge.ldb = 1024; ge.bstrideB = 2097152LL; ge.K = 1024;
  ge.bias = nullptr; ge.adj = adj; ge.dpart = dpart; ge.dpart_r = nullptr;
  ge.C = E; ge.ldc = 2048;
  gemm_occ<M_EXP><<<dim3(64, 16), 256, 0, stream>>>(ge);

  // tmp = (E @ V) / denom; 64x8 = 512 blocks
  GArgs gp = {};
  gp.A = E; gp.B = Vt; gp.lda = 2048; gp.ldb = 2048; gp.bstrideB = 2097152LL; gp.K = 2048;
  gp.bias = nullptr; gp.adj = nullptr; gp.dpart = nullptr; gp.dpart_r = dpart;
  gp.C = tmpb; gp.ldc = 1024;
  gemm_occ<M_PV><<<dim3(64, 8), 256, 0, stream>>>(gp);

  // out = tmp @ Wo + bo  (f32); 64x8 = 512 blocks
  GArgs go = {};
  go.A = tmpb; go.B = WoT; go.lda = 1024; go.ldb = 1024; go.bstrideB = 0; go.K = 1024;
  go.bias = bo; go.adj = nullptr; go.dpart = nullptr; go.dpart_r = nullptr;
  go.C = out; go.ldc = 1024;
  gemm_occ<M_OUT><<<dim3(64, 8), 256, 0, stream>>>(go);
}